// Round 11
// baseline (214.375 us; speedup 1.0000x reference)
//
#include <hip/hip_runtime.h>

#define NDATA 100000
#define KP1 16385            // NCE_K + 1
#define BSZ 64
#define PTOT (BSZ * KP1)     // 1,048,640
#define NCHUNKS 6250         // NDATA / 16 (exact)
#define INV_T (1.0f / 0.07f)
#define ACC_STRIDE 64        // floats; one 256-B cache line per acc group
#define ACC_GROUPS 32
#define SG_NW 2048           // sgemm waves per bank = 512 blocks x 4 (grid fixed!)
#define HSEG 12500           // hist rows per segment (8 segments, 50 KB LDS)
#define BANKF4 3200000       // NDATA*128/4 float4 per bank

typedef short short8 __attribute__((ext_vector_type(8)));
typedef float f32x4 __attribute__((ext_vector_type(4)));

__device__ __forceinline__ float wave_reduce64(float v) {
    #pragma unroll
    for (int off = 32; off >= 1; off >>= 1) v += __shfl_xor(v, off);
    return v;
}

__device__ __forceinline__ float group_reduce16(float v) {
    v += __shfl_xor(v, 8); v += __shfl_xor(v, 4);
    v += __shfl_xor(v, 2); v += __shfl_xor(v, 1);
    return v;
}

__device__ __forceinline__ unsigned short f2bf(float f) {
    unsigned u = __float_as_uint(f);
    u += 0x7FFFu + ((u >> 16) & 1u);   // round-to-nearest-even
    return (unsigned short)(u >> 16);
}

// bf16-round a float and return it as float (matches MFMA input rounding)
__device__ __forceinline__ float bfm(float x) {
    return __uint_as_float(((unsigned)f2bf(x)) << 16);
}

__device__ __forceinline__ short8 pack_bf16(float4 lo, float4 hi) {
    short8 r;
    r[0] = (short)f2bf(lo.x); r[1] = (short)f2bf(lo.y);
    r[2] = (short)f2bf(lo.z); r[3] = (short)f2bf(lo.w);
    r[4] = (short)f2bf(hi.x); r[5] = (short)f2bf(hi.y);
    r[6] = (short)f2bf(hi.z); r[7] = (short)f2bf(hi.w);
    return r;
}

__device__ __forceinline__ float dot4(float4 a, float4 b, float acc) {
    acc = fmaf(a.x, b.x, acc);
    acc = fmaf(a.y, b.y, acc);
    acc = fmaf(a.z, b.z, acc);
    return fmaf(a.w, b.w, acc);
}

// bf16-rounded 8-element partial dot (two float4 pairs)
__device__ __forceinline__ float dot8bf(const float4* a, const float4* v, int li, float d) {
    #pragma unroll
    for (int h = 0; h < 2; ++h) {
        const float4 x = a[li * 2 + h], y = v[li * 2 + h];
        d = fmaf(bfm(x.x), bfm(y.x), d);
        d = fmaf(bfm(x.y), bfm(y.y), d);
        d = fmaf(bfm(x.z), bfm(y.z), d);
        d = fmaf(bfm(x.w), bfm(y.w), d);
    }
    return d;
}

// ---------------- L3-warm + ground-truth streaming probe ---------------------
// Textbook grid-stride float4 read of BOTH banks, TWICE (204.8 MB). 2048
// blocks (8/CU). Decision readout via top-5 visibility (cut ~43 us):
//   visible  <=> service < ~4.7 TB/s  => platform streaming wall => sgemm ~floor
//   invisible => service >= 4.7 TB/s  => sgemm's pattern indicted => keep going
// Side effect: warms L3 with the banks right before sgemm (watch sgemm FETCH).
__global__ __launch_bounds__(256) void l3warm_kernel(
    const float* __restrict__ m1, const float* __restrict__ m2,
    float* __restrict__ dst)
{
    const int t = threadIdx.x;
    const int gid = blockIdx.x * 256 + t;          // 524288 threads
    const float4* p1 = (const float4*)m1;
    const float4* p2 = (const float4*)m2;
    float s = 0.0f;
    #pragma unroll 2
    for (int pass = 0; pass < 2; ++pass) {
        for (int i = gid; i < BANKF4; i += 524288) {
            const float4 a = p1[i];
            const float4 b = p2[i];
            s += (a.x + a.y) + (a.z + a.w) + (b.x + b.y) + (b.z + b.w);
        }
    }
    s = wave_reduce64(s);
    __shared__ float r[4];
    if ((t & 63) == 0) r[t >> 6] = s;
    __syncthreads();
    if (t == 0) dst[blockIdx.x] = r[0] + r[1] + r[2] + r[3];
}

// ---------------- fused embed + hist (independent block roles) ---------------
// Blocks 0..127: hist (long pole, dispatched first). LDS histogram of
// negatives, ILP-batched loads. Output cnt_w[w][row], byte j = multiplicity
// for b=4w+j.
// Blocks 128..1151: embed (bx'=bx-128: dq=bx'>>5, b-pair=bx'&31). Raw dots ->
// vraw; per-dq n^2 partials -> n2part (plain stores, no atomics). Blocks
// 128..135 also zero acc.
__global__ __launch_bounds__(256) void embedhist_kernel(
    const float* __restrict__ fs, const float* __restrict__ ft,
    const float* __restrict__ Ws, const float* __restrict__ bs,
    const float* __restrict__ Wt, const float* __restrict__ bt,
    const int* __restrict__ cidx,
    float* __restrict__ vraw_s, float* __restrict__ vraw_t,
    float* __restrict__ n2part, unsigned* __restrict__ cntw,
    float* __restrict__ acc)
{
    const int t = threadIdx.x;
    __shared__ __align__(16) unsigned char smem[50048];

    if (blockIdx.x < 128) {                    // ---- hist role ----
        unsigned* h = (unsigned*)smem;         // 50 KB
        const int w   = blockIdx.x >> 3;       // 0..15
        const int seg = blockIdx.x & 7;        // 0..7
        const int r0  = seg * HSEG;

        for (int i = t; i < HSEG; i += 256) h[i] = 0;
        __syncthreads();

        #pragma unroll
        for (int j2 = 0; j2 < 4; ++j2) {
            const int b = 4 * w + j2;
            const unsigned inc = 1u << (8 * j2);
            const int* __restrict__ cp = cidx + (size_t)b * KP1 + 1;  // k=1..16384
            for (int bi = 0; bi < 8; ++bi) {   // 8 batches x 8 independent loads
                int v[8];
                #pragma unroll
                for (int u = 0; u < 8; ++u)
                    v[u] = cp[bi * 2048 + u * 256 + t];
                #pragma unroll
                for (int u = 0; u < 8; ++u) {
                    const unsigned rr = (unsigned)(v[u] - r0);
                    if (rr < HSEG) atomicAdd(&h[rr], inc);
                }
            }
        }
        __syncthreads();

        unsigned* __restrict__ dstp = cntw + (size_t)w * NDATA + r0;
        for (int i = t; i < HSEG; i += 256) dstp[i] = h[i];
        return;
    }

    // ---- embed role ----
    const int bx = blockIdx.x - 128;
    if (bx < 8) acc[bx * 256 + t] = 0.0f;      // zero acc (2048 floats)

    float4* FS = (float4*)smem;                // 512  (8 KB)
    float4* FT = (float4*)(smem + 8192);       // 1024 (16 KB)
    float*  NR = (float*)(smem + 24576);       // [4][4] partial squares

    const int dq = bx >> 5;                    // 0..31 (dims dq*4..dq*4+3)
    const int b0 = (bx & 31) * 2;

    for (int q = t; q < 512; q += 256) {
        const int b = q >> 8, i = q & 255;
        FS[q] = ((const float4*)(fs + (size_t)(b0 + b) * 1024))[i];
    }
    for (int q = t; q < 1024; q += 256) {
        const int b = q >> 9, i = q & 511;
        FT[q] = ((const float4*)(ft + (size_t)(b0 + b) * 2048))[i];
    }
    __syncthreads();

    const int w = t >> 6, lane = t & 63;
    const int d = dq * 4 + w;                  // one dim per wave

    {   // s-side
        const float4* wrow = (const float4*)(Ws + (size_t)d * 1024);
        float a0 = 0.0f, a1 = 0.0f;
        #pragma unroll
        for (int i = 0; i < 4; ++i) {
            const float4 wv = wrow[i * 64 + lane];
            a0 = dot4(wv, FS[i * 64 + lane], a0);
            a1 = dot4(wv, FS[256 + i * 64 + lane], a1);
        }
        a0 = wave_reduce64(a0) + bs[d];
        a1 = wave_reduce64(a1) + bs[d];
        if (lane == 0) {
            vraw_s[(size_t)b0 * 128 + d]       = a0;
            vraw_s[(size_t)(b0 + 1) * 128 + d] = a1;
            NR[w * 4 + 0] = a0 * a0;
            NR[w * 4 + 1] = a1 * a1;
        }
    }
    {   // t-side
        const float4* wrow = (const float4*)(Wt + (size_t)d * 2048);
        float a0 = 0.0f, a1 = 0.0f;
        #pragma unroll
        for (int i = 0; i < 8; ++i) {
            const float4 wv = wrow[i * 64 + lane];
            a0 = dot4(wv, FT[i * 64 + lane], a0);
            a1 = dot4(wv, FT[512 + i * 64 + lane], a1);
        }
        a0 = wave_reduce64(a0) + bt[d];
        a1 = wave_reduce64(a1) + bt[d];
        if (lane == 0) {
            vraw_t[(size_t)b0 * 128 + d]       = a0;
            vraw_t[(size_t)(b0 + 1) * 128 + d] = a1;
            NR[w * 4 + 2] = a0 * a0;
            NR[w * 4 + 3] = a1 * a1;
        }
    }
    __syncthreads();
    if (t < 4) {
        // t=0: s-side b0 | t=1: s-side b0+1 | t=2: t-side b0 | t=3: t-side b0+1
        const float v = NR[0 * 4 + t] + NR[1 * 4 + t] + NR[2 * 4 + t] + NR[3 * 4 + t];
        const int side = (t < 2) ? 1 : 0;      // side0 = t-bank, side1 = s-bank
        const int bb = b0 + (t & 1);
        n2part[side * 2048 + bb * 32 + dq] = v;
    }
}

// ---------------- fused bf16 MFMA GEMM + weighted exp-sum (no S array) -------
// lane (m,q4) reg j of the (swapped) D-frag = S[row0+m][b = n*16+q4*4+j]
// (mapping verified R2-R9). 2-buffer register pipeline; grid (512,2) = 2048
// waves/bank; 3 unconditional chunks + wave-uniform-guarded 4th. Prologue
// computes scale[b] = INV_T*rsqrt(sum_dq n2part).
#define SG_ISSUE(AB, CB, CID)                                                \
  {                                                                          \
    const int r0_ = (CID) << 4;                                              \
    const float4* ar_ = (const float4*)(bankp + (size_t)(r0_ + m) * 128);    \
    _Pragma("unroll")                                                        \
    for (int kk = 0; kk < 4; ++kk) {                                         \
      AB[kk * 2]     = ar_[(kk * 4 + q4) * 2];                               \
      AB[kk * 2 + 1] = ar_[(kk * 4 + q4) * 2 + 1];                           \
    }                                                                        \
    _Pragma("unroll")                                                        \
    for (int n = 0; n < 4; ++n)                                              \
      CB[n] = cntw[(size_t)(n * 4 + q4) * NDATA + (r0_ + m)];                \
  }

#define SG_PROCESS(AB, CB)                                                   \
  {                                                                          \
    short8 af_[4];                                                           \
    _Pragma("unroll")                                                        \
    for (int kk = 0; kk < 4; ++kk)                                           \
      af_[kk] = pack_bf16(AB[kk * 2], AB[kk * 2 + 1]);                       \
    _Pragma("unroll")                                                        \
    for (int n = 0; n < 4; ++n) {                                            \
      f32x4 av = {0.f, 0.f, 0.f, 0.f};                                       \
      _Pragma("unroll")                                                      \
      for (int kk = 0; kk < 4; ++kk)                                         \
        av = __builtin_amdgcn_mfma_f32_16x16x32_bf16(bfv[n][kk], af_[kk], av, 0, 0, 0); \
      const unsigned cw_ = CB[n];                                            \
      _Pragma("unroll")                                                      \
      for (int j = 0; j < 4; ++j) {                                          \
        const float fm_ = (float)((cw_ >> (8 * j)) & 255u);                  \
        const float e_  = __expf(av[j] * scv[n][j]);                         \
        se  = fmaf(e_, fm_, se);                                             \
        se2 = fmaf(e_ * fm_, e_, se2);                                       \
      }                                                                      \
    }                                                                        \
  }

__global__ __launch_bounds__(256) void sgemm_kernel(
    const float* __restrict__ m1, const float* __restrict__ m2,
    const float* __restrict__ vraw_s, const float* __restrict__ vraw_t,
    const float* __restrict__ n2part,
    const unsigned* __restrict__ cntw,
    float* __restrict__ acc)
{
    const int t = threadIdx.x;
    const int bank = blockIdx.y;
    const float* __restrict__ bankp = bank ? m2 : m1;
    const float* __restrict__ vp    = bank ? vraw_s : vraw_t;

    __shared__ float scl[64];
    {   // prologue: scale[b] = INV_T * rsqrt(sum_dq n2part[bank][b][dq])
        const int tb = t >> 2, tg = t & 3;     // 4 threads per b
        const float* np = n2part + bank * 2048 + tb * 32 + tg * 8;
        float s = 0.0f;
        #pragma unroll
        for (int j = 0; j < 8; ++j) s += np[j];
        s += __shfl_xor(s, 1);
        s += __shfl_xor(s, 2);
        if (tg == 0) scl[tb] = INV_T * rsqrtf(s);
    }
    __syncthreads();

    const int lane = t & 63;
    const int m  = lane & 15;
    const int q4 = lane >> 4;

    // V fragments, register-resident
    short8 bfv[4][4];
    #pragma unroll
    for (int n = 0; n < 4; ++n) {
        const float4* vrow = (const float4*)(vp + (size_t)(n * 16 + m) * 128);
        #pragma unroll
        for (int kk = 0; kk < 4; ++kk) {
            const float4 lo = vrow[(kk * 4 + q4) * 2];
            const float4 hi = vrow[(kk * 4 + q4) * 2 + 1];
            bfv[n][kk] = pack_bf16(lo, hi);
        }
    }

    // per-lane scales for its 16 b's
    f32x4 scv[4];
    #pragma unroll
    for (int n = 0; n < 4; ++n) {
        #pragma unroll
        for (int j = 0; j < 4; ++j) scv[n][j] = scl[n * 16 + q4 * 4 + j];
    }

    float se = 0.0f, se2 = 0.0f;

    const int wave = (blockIdx.x << 2) | (t >> 6);   // 0..2047

    float4 aA[8], aB[8];
    unsigned cA[4], cB[4];

    SG_ISSUE(aA, cA, wave);
    SG_ISSUE(aB, cB, wave + SG_NW);
    SG_PROCESS(aA, cA);
    SG_ISSUE(aA, cA, wave + 2 * SG_NW);
    SG_PROCESS(aB, cB);
    if (wave + 3 * SG_NW < NCHUNKS) {                // wave-uniform (106 waves)
        SG_ISSUE(aB, cB, wave + 3 * SG_NW);
        SG_PROCESS(aA, cA);
        SG_PROCESS(aB, cB);
    } else {
        SG_PROCESS(aA, cA);
    }

    se  = wave_reduce64(se);
    se2 = wave_reduce64(se2);
    __shared__ float red[4][2];
    if (lane == 0) { red[t >> 6][0] = se; red[t >> 6][1] = se2; }
    __syncthreads();
    if (t < 2) {
        const float s = red[0][t] + red[1][t] + red[2][t] + red[3][t];
        atomicAdd(&acc[(blockIdx.x & (ACC_GROUPS - 1)) * ACC_STRIDE + bank * 2 + t], s);
    }
}

// ---------------- final: positives (direct dots) + closed-form negatives -----
__global__ __launch_bounds__(256) void final_kernel(
    const int* __restrict__ idx,
    const float* __restrict__ m1, const float* __restrict__ m2,
    const float* __restrict__ vraw_t, const float* __restrict__ vraw_s,
    const float* __restrict__ n2part,
    const float* __restrict__ acc, float* __restrict__ out)
{
    const int t = threadIdx.x, wave = t >> 6, lane = t & 63, g = lane >> 4, li = lane & 15;
    __shared__ float sctl[64], scsl[64];
    __shared__ float e1s[64], e2s[64];

    if (t < 128) {                             // scales from n2part
        const int side = t >> 6, b = t & 63;   // side0 = t-bank, side1 = s-bank
        const float* np = n2part + side * 2048 + b * 32;
        float s = 0.0f;
        for (int j = 0; j < 32; ++j) s += np[j];
        (side ? scsl : sctl)[b] = INV_T * rsqrtf(s);
    }
    __syncthreads();

    #pragma unroll
    for (int i = 0; i < 4; ++i) {
        const int b = wave * 16 + i * 4 + g;
        const int row = idx[b];
        float dT = dot8bf((const float4*)(m1 + (size_t)row * 128),
                          (const float4*)(vraw_t + (size_t)b * 128), li, 0.f);
        float dS = dot8bf((const float4*)(m2 + (size_t)row * 128),
                          (const float4*)(vraw_s + (size_t)b * 128), li, 0.f);
        dT = group_reduce16(dT);
        dS = group_reduce16(dS);
        if (li == 0) {
            e1s[b] = __expf(dT * sctl[b]);
            e2s[b] = __expf(dS * scsl[b]);
        }
    }
    __syncthreads();

    if (t < 64) {
        const int b = t;
        const float c = 0.16384f + 1e-7f;
        const float e1p = e1s[b], e2p = e2s[b];

        const float pseT = wave_reduce64(e1p);
        const float pseS = wave_reduce64(e2p);

        float seT_neg = 0.f, se2T_neg = 0.f, seS_neg = 0.f, se2S_neg = 0.f;
        for (int s = 0; s < ACC_GROUPS; ++s) {
            seT_neg  += acc[s * ACC_STRIDE + 0];
            se2T_neg += acc[s * ACC_STRIDE + 1];
            seS_neg  += acc[s * ACC_STRIDE + 2];
            se2S_neg += acc[s * ACC_STRIDE + 3];
        }

        const float zn = (float)PTOT / (float)NDATA;
        const float invZt = zn / (seT_neg + pseT);   // Z-sum includes positives
        const float invZs = zn / (seS_neg + pseS);

        const float PB = (float)(PTOT - BSZ);        // 1,048,576
        const float LOG_MPN_C = -6.1035156e-7f;      // ln(mPn / (mPn + 1e-7))
        const float ic = 1.0f / c;

        const float negT = PB * LOG_MPN_C
                         - seT_neg * invZt * ic
                         + 0.5f * se2T_neg * invZt * invZt * ic * ic;
        const float negS = PB * LOG_MPN_C
                         - seS_neg * invZs * ic
                         + 0.5f * se2S_neg * invZs * invZs * ic * ic;

        const float x0t = e1p * invZt, x0s = e2p * invZs;
        float pos = __logf(x0t / (x0t + c)) + __logf(x0s / (x0s + c));
        pos = wave_reduce64(pos);

        if (b == 0) out[0] = -(negT + negS + pos) * (1.0f / 64.0f);
    }
}

extern "C" void kernel_launch(void* const* d_in, const int* in_sizes, int n_in,
                              void* d_out, int out_size, void* d_ws, size_t ws_size,
                              hipStream_t stream) {
    const float* fs   = (const float*)d_in[0];
    const float* ft   = (const float*)d_in[1];
    const int*   idx  = (const int*)d_in[2];
    const int*   cidx = (const int*)d_in[3];
    const float* Ws   = (const float*)d_in[4];
    const float* bs   = (const float*)d_in[5];
    const float* Wt   = (const float*)d_in[6];
    const float* bt   = (const float*)d_in[7];
    const float* m1   = (const float*)d_in[8];
    const float* m2   = (const float*)d_in[9];
    float* out = (float*)d_out;

    // ws layout (float index):
    //   [0..2048)            acc (32 groups x 64-float line; zeroed by embed blocks)
    //   [2048..6144)         n2part (2 sides x 64 b x 32 dq)
    //   [6144..8192)         probe partial sums (2048)
    //   [8192..1608192)      cnt_w (16 w-groups x 100000 u32 = 6.4 MB; fully written)
    //   [1608192..1616384)   vraw_s
    //   [1616384..1624576)   vraw_t
    float* ws      = (float*)d_ws;
    float* acc     = ws;
    float* n2part  = ws + 2048;
    float* pdst    = ws + 6144;
    unsigned* cntw = (unsigned*)(ws + 8192);
    float* vraw_s  = ws + 1608192;
    float* vraw_t  = ws + 1616384;

    embedhist_kernel<<<dim3(1152), dim3(256), 0, stream>>>(
        fs, ft, Ws, bs, Wt, bt, cidx, vraw_s, vraw_t, n2part, cntw, acc);
    l3warm_kernel<<<dim3(2048), dim3(256), 0, stream>>>(m1, m2, pdst);
    sgemm_kernel<<<dim3(512, 2), dim3(256), 0, stream>>>(   // grid MUST match SG_NW
        m1, m2, vraw_s, vraw_t, n2part, cntw, acc);
    final_kernel<<<dim3(1), dim3(256), 0, stream>>>(
        idx, m1, m2, vraw_t, vraw_s, n2part, acc, out);
}

// Round 12
// 205.367 us; speedup vs baseline: 1.0439x; 1.0439x over previous
//
#include <hip/hip_runtime.h>

#define NDATA 100000
#define KP1 16385            // NCE_K + 1
#define BSZ 64
#define PTOT (BSZ * KP1)     // 1,048,640
#define NCHUNKS 6250         // NDATA / 16 (exact)
#define INV_T (1.0f / 0.07f)
#define ACC_STRIDE 64        // floats; one 256-B cache line per acc group
#define ACC_GROUPS 32
#define SG_NW 3128           // sgemm waves per bank = 782 blocks x 4 (grid fixed!)
#define SG_TAIL 3122         // waves doing a 2nd chunk: 6250 - 3128
#define HSEG 12500           // hist rows per segment (8 segments, 50 KB LDS)

typedef short short8 __attribute__((ext_vector_type(8)));
typedef float f32x4 __attribute__((ext_vector_type(4)));

__device__ __forceinline__ float wave_reduce64(float v) {
    #pragma unroll
    for (int off = 32; off >= 1; off >>= 1) v += __shfl_xor(v, off);
    return v;
}

__device__ __forceinline__ float group_reduce16(float v) {
    v += __shfl_xor(v, 8); v += __shfl_xor(v, 4);
    v += __shfl_xor(v, 2); v += __shfl_xor(v, 1);
    return v;
}

__device__ __forceinline__ unsigned short f2bf(float f) {
    unsigned u = __float_as_uint(f);
    u += 0x7FFFu + ((u >> 16) & 1u);   // round-to-nearest-even
    return (unsigned short)(u >> 16);
}

// bf16-round a float and return it as float (matches MFMA input rounding)
__device__ __forceinline__ float bfm(float x) {
    return __uint_as_float(((unsigned)f2bf(x)) << 16);
}

__device__ __forceinline__ short8 pack_bf16(float4 lo, float4 hi) {
    short8 r;
    r[0] = (short)f2bf(lo.x); r[1] = (short)f2bf(lo.y);
    r[2] = (short)f2bf(lo.z); r[3] = (short)f2bf(lo.w);
    r[4] = (short)f2bf(hi.x); r[5] = (short)f2bf(hi.y);
    r[6] = (short)f2bf(hi.z); r[7] = (short)f2bf(hi.w);
    return r;
}

__device__ __forceinline__ float dot4(float4 a, float4 b, float acc) {
    acc = fmaf(a.x, b.x, acc);
    acc = fmaf(a.y, b.y, acc);
    acc = fmaf(a.z, b.z, acc);
    return fmaf(a.w, b.w, acc);
}

// bf16-rounded 8-element partial dot (two float4 pairs)
__device__ __forceinline__ float dot8bf(const float4* a, const float4* v, int li, float d) {
    #pragma unroll
    for (int h = 0; h < 2; ++h) {
        const float4 x = a[li * 2 + h], y = v[li * 2 + h];
        d = fmaf(bfm(x.x), bfm(y.x), d);
        d = fmaf(bfm(x.y), bfm(y.y), d);
        d = fmaf(bfm(x.z), bfm(y.z), d);
        d = fmaf(bfm(x.w), bfm(y.w), d);
    }
    return d;
}

// ---------------- fused embed + hist (independent block roles) ---------------
// Blocks 0..127: hist. LDS histogram of negatives, ILP-batched loads.
// Output cnt_w[w][row], byte j = multiplicity for b=4w+j.
// Blocks 128..1151: embed. Raw dots -> vraw; per-dq n^2 partials -> n2part.
// Blocks 128..135 also zero acc.
__global__ __launch_bounds__(256) void embedhist_kernel(
    const float* __restrict__ fs, const float* __restrict__ ft,
    const float* __restrict__ Ws, const float* __restrict__ bs,
    const float* __restrict__ Wt, const float* __restrict__ bt,
    const int* __restrict__ cidx,
    float* __restrict__ vraw_s, float* __restrict__ vraw_t,
    float* __restrict__ n2part, unsigned* __restrict__ cntw,
    float* __restrict__ acc)
{
    const int t = threadIdx.x;
    __shared__ __align__(16) unsigned char smem[50048];

    if (blockIdx.x < 128) {                    // ---- hist role ----
        unsigned* h = (unsigned*)smem;         // 50 KB
        const int w   = blockIdx.x >> 3;       // 0..15
        const int seg = blockIdx.x & 7;        // 0..7
        const int r0  = seg * HSEG;

        for (int i = t; i < HSEG; i += 256) h[i] = 0;
        __syncthreads();

        #pragma unroll
        for (int j2 = 0; j2 < 4; ++j2) {
            const int b = 4 * w + j2;
            const unsigned inc = 1u << (8 * j2);
            const int* __restrict__ cp = cidx + (size_t)b * KP1 + 1;  // k=1..16384
            for (int bi = 0; bi < 8; ++bi) {   // 8 batches x 8 independent loads
                int v[8];
                #pragma unroll
                for (int u = 0; u < 8; ++u)
                    v[u] = cp[bi * 2048 + u * 256 + t];
                #pragma unroll
                for (int u = 0; u < 8; ++u) {
                    const unsigned rr = (unsigned)(v[u] - r0);
                    if (rr < HSEG) atomicAdd(&h[rr], inc);
                }
            }
        }
        __syncthreads();

        unsigned* __restrict__ dstp = cntw + (size_t)w * NDATA + r0;
        for (int i = t; i < HSEG; i += 256) dstp[i] = h[i];
        return;
    }

    // ---- embed role ----
    const int bx = blockIdx.x - 128;
    if (bx < 8) acc[bx * 256 + t] = 0.0f;      // zero acc (2048 floats)

    float4* FS = (float4*)smem;                // 512  (8 KB)
    float4* FT = (float4*)(smem + 8192);       // 1024 (16 KB)
    float*  NR = (float*)(smem + 24576);       // [4][4] partial squares

    const int dq = bx >> 5;                    // 0..31 (dims dq*4..dq*4+3)
    const int b0 = (bx & 31) * 2;

    for (int q = t; q < 512; q += 256) {
        const int b = q >> 8, i = q & 255;
        FS[q] = ((const float4*)(fs + (size_t)(b0 + b) * 1024))[i];
    }
    for (int q = t; q < 1024; q += 256) {
        const int b = q >> 9, i = q & 511;
        FT[q] = ((const float4*)(ft + (size_t)(b0 + b) * 2048))[i];
    }
    __syncthreads();

    const int w = t >> 6, lane = t & 63;
    const int d = dq * 4 + w;                  // one dim per wave

    {   // s-side
        const float4* wrow = (const float4*)(Ws + (size_t)d * 1024);
        float a0 = 0.0f, a1 = 0.0f;
        #pragma unroll
        for (int i = 0; i < 4; ++i) {
            const float4 wv = wrow[i * 64 + lane];
            a0 = dot4(wv, FS[i * 64 + lane], a0);
            a1 = dot4(wv, FS[256 + i * 64 + lane], a1);
        }
        a0 = wave_reduce64(a0) + bs[d];
        a1 = wave_reduce64(a1) + bs[d];
        if (lane == 0) {
            vraw_s[(size_t)b0 * 128 + d]       = a0;
            vraw_s[(size_t)(b0 + 1) * 128 + d] = a1;
            NR[w * 4 + 0] = a0 * a0;
            NR[w * 4 + 1] = a1 * a1;
        }
    }
    {   // t-side
        const float4* wrow = (const float4*)(Wt + (size_t)d * 2048);
        float a0 = 0.0f, a1 = 0.0f;
        #pragma unroll
        for (int i = 0; i < 8; ++i) {
            const float4 wv = wrow[i * 64 + lane];
            a0 = dot4(wv, FT[i * 64 + lane], a0);
            a1 = dot4(wv, FT[512 + i * 64 + lane], a1);
        }
        a0 = wave_reduce64(a0) + bt[d];
        a1 = wave_reduce64(a1) + bt[d];
        if (lane == 0) {
            vraw_t[(size_t)b0 * 128 + d]       = a0;
            vraw_t[(size_t)(b0 + 1) * 128 + d] = a1;
            NR[w * 4 + 2] = a0 * a0;
            NR[w * 4 + 3] = a1 * a1;
        }
    }
    __syncthreads();
    if (t < 4) {
        const float v = NR[0 * 4 + t] + NR[1 * 4 + t] + NR[2 * 4 + t] + NR[3 * 4 + t];
        const int side = (t < 2) ? 1 : 0;      // side0 = t-bank, side1 = s-bank
        const int bb = b0 + (t & 1);
        n2part[side * 2048 + bb * 32 + dq] = v;
    }
}

// ---------------- fused bf16 MFMA GEMM + weighted exp-sum (occupancy build) --
// R11 probe verdict: platform streams at 2.35 TB/s HBM / 4.84 TB/s combined at
// 71% occupancy; sgemm got 2.9 TB/s combined at 16% (VGPR=116-capped). This
// version buys occupancy: V fragments live in XOR-swizzled LDS (not 64 VGPRs),
// single A-buffer (no 32-VGPR double buffer; TLP replaces ILP like the probe),
// __launch_bounds__(256,5) caps VGPR at 102 -> 5+ waves/SIMD. Grid (782,2) =
// 3128 waves/bank, 2 chunks/wave (wave-uniform tail), ~6 blocks/CU resident.
// Swizzle: ushort idx = (row*128 + slot*8) ^ ((row&7)<<3) -> each (n,kk) wave
// read lands uniformly 8 lanes per 4-bank slot = the b128 throughput floor.
// mapping unchanged (verified R2-R9): lane (m,q4) reg j = S[row0+m][n*16+q4*4+j].
#define SGP(CID)                                                             \
  {                                                                          \
    const int r0_ = (CID) << 4;                                              \
    const float4* ar_ = (const float4*)(bankp + (size_t)(r0_ + m) * 128);    \
    float4 a_[8];                                                            \
    _Pragma("unroll")                                                        \
    for (int kk = 0; kk < 4; ++kk) {                                         \
      a_[kk * 2]     = ar_[(kk * 4 + q4) * 2];                               \
      a_[kk * 2 + 1] = ar_[(kk * 4 + q4) * 2 + 1];                           \
    }                                                                        \
    unsigned c_[4];                                                          \
    _Pragma("unroll")                                                        \
    for (int n = 0; n < 4; ++n)                                              \
      c_[n] = cntw[(size_t)(n * 4 + q4) * NDATA + (r0_ + m)];                \
    short8 af_[4];                                                           \
    _Pragma("unroll")                                                        \
    for (int kk = 0; kk < 4; ++kk)                                           \
      af_[kk] = pack_bf16(a_[kk * 2], a_[kk * 2 + 1]);                       \
    _Pragma("unroll")                                                        \
    for (int n = 0; n < 4; ++n) {                                            \
      f32x4 av = {0.f, 0.f, 0.f, 0.f};                                       \
      _Pragma("unroll")                                                      \
      for (int kk = 0; kk < 4; ++kk) {                                       \
        const int row_ = n * 16 + m;                                         \
        const short8 bv = *(const short8*)&Vb[((row_ * 128 + (kk * 4 + q4) * 8) ^ ((m & 7) << 3))]; \
        av = __builtin_amdgcn_mfma_f32_16x16x32_bf16(bv, af_[kk], av, 0, 0, 0); \
      }                                                                      \
      const unsigned cw_ = c_[n];                                            \
      _Pragma("unroll")                                                      \
      for (int j = 0; j < 4; ++j) {                                          \
        const float fm_ = (float)((cw_ >> (8 * j)) & 255u);                  \
        const float e_  = __expf(av[j] * scl[n * 16 + q4 * 4 + j]);          \
        se  = fmaf(e_, fm_, se);                                             \
        se2 = fmaf(e_ * fm_, e_, se2);                                       \
      }                                                                      \
    }                                                                        \
  }

__global__ __launch_bounds__(256, 5) void sgemm_kernel(
    const float* __restrict__ m1, const float* __restrict__ m2,
    const float* __restrict__ vraw_s, const float* __restrict__ vraw_t,
    const float* __restrict__ n2part,
    const unsigned* __restrict__ cntw,
    float* __restrict__ acc)
{
    const int t = threadIdx.x;
    const int bank = blockIdx.y;
    const float* __restrict__ bankp = bank ? m2 : m1;
    const float* __restrict__ vp    = bank ? vraw_s : vraw_t;

    __shared__ __align__(16) unsigned short Vb[8192];   // 64x128 bf16, swizzled
    __shared__ float scl[64];
    __shared__ float red[4][2];

    {   // stage V -> LDS bf16 (XOR-swizzled); same RNE as before -> same numerics
        const int r = t >> 2;                  // 0..63
        const int s0 = (t & 3) * 4;            // slot base (slots 0..15 of 8 bf16)
        const float4* vr = (const float4*)(vp + (size_t)r * 128);
        #pragma unroll
        for (int q = 0; q < 4; ++q) {
            const int s = s0 + q;
            const float4 lo = vr[s * 2];
            const float4 hi = vr[s * 2 + 1];
            *(short8*)&Vb[((r * 128 + s * 8) ^ ((r & 7) << 3))] = pack_bf16(lo, hi);
        }
    }
    {   // prologue: scale[b] = INV_T * rsqrt(sum_dq n2part[bank][b][dq])
        const int tb = t >> 2, tg = t & 3;     // 4 threads per b
        const float* np = n2part + bank * 2048 + tb * 32 + tg * 8;
        float s = 0.0f;
        #pragma unroll
        for (int j = 0; j < 8; ++j) s += np[j];
        s += __shfl_xor(s, 1);
        s += __shfl_xor(s, 2);
        if (tg == 0) scl[tb] = INV_T * rsqrtf(s);
    }
    __syncthreads();

    const int lane = t & 63;
    const int m  = lane & 15;
    const int q4 = lane >> 4;

    float se = 0.0f, se2 = 0.0f;

    const int wave = (blockIdx.x << 2) | (t >> 6);   // 0..3127

    SGP(wave);
    if (wave < SG_TAIL) {                            // wave-uniform guard
        SGP(wave + SG_NW);
    }

    se  = wave_reduce64(se);
    se2 = wave_reduce64(se2);
    if (lane == 0) { red[t >> 6][0] = se; red[t >> 6][1] = se2; }
    __syncthreads();
    if (t < 2) {
        const float s = red[0][t] + red[1][t] + red[2][t] + red[3][t];
        atomicAdd(&acc[(blockIdx.x & (ACC_GROUPS - 1)) * ACC_STRIDE + bank * 2 + t], s);
    }
}

// ---------------- final: positives (direct dots) + closed-form negatives -----
__global__ __launch_bounds__(256) void final_kernel(
    const int* __restrict__ idx,
    const float* __restrict__ m1, const float* __restrict__ m2,
    const float* __restrict__ vraw_t, const float* __restrict__ vraw_s,
    const float* __restrict__ n2part,
    const float* __restrict__ acc, float* __restrict__ out)
{
    const int t = threadIdx.x, wave = t >> 6, lane = t & 63, g = lane >> 4, li = lane & 15;
    __shared__ float sctl[64], scsl[64];
    __shared__ float e1s[64], e2s[64];

    if (t < 128) {                             // scales from n2part
        const int side = t >> 6, b = t & 63;   // side0 = t-bank, side1 = s-bank
        const float* np = n2part + side * 2048 + b * 32;
        float s = 0.0f;
        for (int j = 0; j < 32; ++j) s += np[j];
        (side ? scsl : sctl)[b] = INV_T * rsqrtf(s);
    }
    __syncthreads();

    #pragma unroll
    for (int i = 0; i < 4; ++i) {
        const int b = wave * 16 + i * 4 + g;
        const int row = idx[b];
        float dT = dot8bf((const float4*)(m1 + (size_t)row * 128),
                          (const float4*)(vraw_t + (size_t)b * 128), li, 0.f);
        float dS = dot8bf((const float4*)(m2 + (size_t)row * 128),
                          (const float4*)(vraw_s + (size_t)b * 128), li, 0.f);
        dT = group_reduce16(dT);
        dS = group_reduce16(dS);
        if (li == 0) {
            e1s[b] = __expf(dT * sctl[b]);
            e2s[b] = __expf(dS * scsl[b]);
        }
    }
    __syncthreads();

    if (t < 64) {
        const int b = t;
        const float c = 0.16384f + 1e-7f;
        const float e1p = e1s[b], e2p = e2s[b];

        const float pseT = wave_reduce64(e1p);
        const float pseS = wave_reduce64(e2p);

        float seT_neg = 0.f, se2T_neg = 0.f, seS_neg = 0.f, se2S_neg = 0.f;
        for (int s = 0; s < ACC_GROUPS; ++s) {
            seT_neg  += acc[s * ACC_STRIDE + 0];
            se2T_neg += acc[s * ACC_STRIDE + 1];
            seS_neg  += acc[s * ACC_STRIDE + 2];
            se2S_neg += acc[s * ACC_STRIDE + 3];
        }

        const float zn = (float)PTOT / (float)NDATA;
        const float invZt = zn / (seT_neg + pseT);   // Z-sum includes positives
        const float invZs = zn / (seS_neg + pseS);

        const float PB = (float)(PTOT - BSZ);        // 1,048,576
        const float LOG_MPN_C = -6.1035156e-7f;      // ln(mPn / (mPn + 1e-7))
        const float ic = 1.0f / c;

        const float negT = PB * LOG_MPN_C
                         - seT_neg * invZt * ic
                         + 0.5f * se2T_neg * invZt * invZt * ic * ic;
        const float negS = PB * LOG_MPN_C
                         - seS_neg * invZs * ic
                         + 0.5f * se2S_neg * invZs * invZs * ic * ic;

        const float x0t = e1p * invZt, x0s = e2p * invZs;
        float pos = __logf(x0t / (x0t + c)) + __logf(x0s / (x0s + c));
        pos = wave_reduce64(pos);

        if (b == 0) out[0] = -(negT + negS + pos) * (1.0f / 64.0f);
    }
}

extern "C" void kernel_launch(void* const* d_in, const int* in_sizes, int n_in,
                              void* d_out, int out_size, void* d_ws, size_t ws_size,
                              hipStream_t stream) {
    const float* fs   = (const float*)d_in[0];
    const float* ft   = (const float*)d_in[1];
    const int*   idx  = (const int*)d_in[2];
    const int*   cidx = (const int*)d_in[3];
    const float* Ws   = (const float*)d_in[4];
    const float* bs   = (const float*)d_in[5];
    const float* Wt   = (const float*)d_in[6];
    const float* bt   = (const float*)d_in[7];
    const float* m1   = (const float*)d_in[8];
    const float* m2   = (const float*)d_in[9];
    float* out = (float*)d_out;

    // ws layout (float index):
    //   [0..2048)            acc (32 groups x 64-float line; zeroed by embed blocks)
    //   [2048..6144)         n2part (2 sides x 64 b x 32 dq)
    //   [6144..8192)         pad
    //   [8192..1608192)      cnt_w (16 w-groups x 100000 u32 = 6.4 MB; fully written)
    //   [1608192..1616384)   vraw_s
    //   [1616384..1624576)   vraw_t
    float* ws      = (float*)d_ws;
    float* acc     = ws;
    float* n2part  = ws + 2048;
    unsigned* cntw = (unsigned*)(ws + 8192);
    float* vraw_s  = ws + 1608192;
    float* vraw_t  = ws + 1616384;

    embedhist_kernel<<<dim3(1152), dim3(256), 0, stream>>>(
        fs, ft, Ws, bs, Wt, bt, cidx, vraw_s, vraw_t, n2part, cntw, acc);
    sgemm_kernel<<<dim3(782, 2), dim3(256), 0, stream>>>(   // grid MUST match SG_NW
        m1, m2, vraw_s, vraw_t, n2part, cntw, acc);
    final_kernel<<<dim3(1), dim3(256), 0, stream>>>(
        idx, m1, m2, vraw_t, vraw_s, n2part, acc, out);
}

// Round 13
// 186.216 us; speedup vs baseline: 1.1512x; 1.1028x over previous
//
#include <hip/hip_runtime.h>

#define NDATA 100000
#define KP1 16385            // NCE_K + 1
#define BSZ 64
#define PTOT (BSZ * KP1)     // 1,048,640
#define NCHUNKS 6250         // NDATA / 16 (exact)
#define INV_T (1.0f / 0.07f)
#define ACC_STRIDE 64        // floats; one 256-B cache line per acc group
#define ACC_GROUPS 32
#define SG_NW 2048           // sgemm waves per bank = 512 blocks x 4 (grid fixed!)
#define HSEG 12500           // hist rows per segment (8 segments, 50 KB LDS)

typedef short short8 __attribute__((ext_vector_type(8)));
typedef float f32x4 __attribute__((ext_vector_type(4)));

__device__ __forceinline__ float wave_reduce64(float v) {
    #pragma unroll
    for (int off = 32; off >= 1; off >>= 1) v += __shfl_xor(v, off);
    return v;
}

__device__ __forceinline__ float group_reduce16(float v) {
    v += __shfl_xor(v, 8); v += __shfl_xor(v, 4);
    v += __shfl_xor(v, 2); v += __shfl_xor(v, 1);
    return v;
}

__device__ __forceinline__ unsigned short f2bf(float f) {
    unsigned u = __float_as_uint(f);
    u += 0x7FFFu + ((u >> 16) & 1u);   // round-to-nearest-even
    return (unsigned short)(u >> 16);
}

// bf16-round a float and return it as float (matches MFMA input rounding)
__device__ __forceinline__ float bfm(float x) {
    return __uint_as_float(((unsigned)f2bf(x)) << 16);
}

__device__ __forceinline__ short8 pack_bf16(float4 lo, float4 hi) {
    short8 r;
    r[0] = (short)f2bf(lo.x); r[1] = (short)f2bf(lo.y);
    r[2] = (short)f2bf(lo.z); r[3] = (short)f2bf(lo.w);
    r[4] = (short)f2bf(hi.x); r[5] = (short)f2bf(hi.y);
    r[6] = (short)f2bf(hi.z); r[7] = (short)f2bf(hi.w);
    return r;
}

__device__ __forceinline__ float dot4(float4 a, float4 b, float acc) {
    acc = fmaf(a.x, b.x, acc);
    acc = fmaf(a.y, b.y, acc);
    acc = fmaf(a.z, b.z, acc);
    return fmaf(a.w, b.w, acc);
}

// bf16-rounded 8-element partial dot (two float4 pairs)
__device__ __forceinline__ float dot8bf(const float4* a, const float4* v, int li, float d) {
    #pragma unroll
    for (int h = 0; h < 2; ++h) {
        const float4 x = a[li * 2 + h], y = v[li * 2 + h];
        d = fmaf(bfm(x.x), bfm(y.x), d);
        d = fmaf(bfm(x.y), bfm(y.y), d);
        d = fmaf(bfm(x.z), bfm(y.z), d);
        d = fmaf(bfm(x.w), bfm(y.w), d);
    }
    return d;
}

// ---------------- fused embed + hist (independent block roles) ---------------
// Blocks 0..127: hist. LDS histogram of negatives, ILP-batched loads.
// Output cnt_w[w][row], byte j = multiplicity for b=4w+j.
// Blocks 128..1151: embed. Raw dots -> vraw; per-dq n^2 partials -> n2part.
// Blocks 128..135 also zero acc.
__global__ __launch_bounds__(256) void embedhist_kernel(
    const float* __restrict__ fs, const float* __restrict__ ft,
    const float* __restrict__ Ws, const float* __restrict__ bs,
    const float* __restrict__ Wt, const float* __restrict__ bt,
    const int* __restrict__ cidx,
    float* __restrict__ vraw_s, float* __restrict__ vraw_t,
    float* __restrict__ n2part, unsigned* __restrict__ cntw,
    float* __restrict__ acc)
{
    const int t = threadIdx.x;
    __shared__ __align__(16) unsigned char smem[50048];

    if (blockIdx.x < 128) {                    // ---- hist role ----
        unsigned* h = (unsigned*)smem;         // 50 KB
        const int w   = blockIdx.x >> 3;       // 0..15
        const int seg = blockIdx.x & 7;        // 0..7
        const int r0  = seg * HSEG;

        for (int i = t; i < HSEG; i += 256) h[i] = 0;
        __syncthreads();

        #pragma unroll
        for (int j2 = 0; j2 < 4; ++j2) {
            const int b = 4 * w + j2;
            const unsigned inc = 1u << (8 * j2);
            const int* __restrict__ cp = cidx + (size_t)b * KP1 + 1;  // k=1..16384
            for (int bi = 0; bi < 8; ++bi) {   // 8 batches x 8 independent loads
                int v[8];
                #pragma unroll
                for (int u = 0; u < 8; ++u)
                    v[u] = cp[bi * 2048 + u * 256 + t];
                #pragma unroll
                for (int u = 0; u < 8; ++u) {
                    const unsigned rr = (unsigned)(v[u] - r0);
                    if (rr < HSEG) atomicAdd(&h[rr], inc);
                }
            }
        }
        __syncthreads();

        unsigned* __restrict__ dstp = cntw + (size_t)w * NDATA + r0;
        for (int i = t; i < HSEG; i += 256) dstp[i] = h[i];
        return;
    }

    // ---- embed role ----
    const int bx = blockIdx.x - 128;
    if (bx < 8) acc[bx * 256 + t] = 0.0f;      // zero acc (2048 floats)

    float4* FS = (float4*)smem;                // 512  (8 KB)
    float4* FT = (float4*)(smem + 8192);       // 1024 (16 KB)
    float*  NR = (float*)(smem + 24576);       // [4][4] partial squares

    const int dq = bx >> 5;                    // 0..31 (dims dq*4..dq*4+3)
    const int b0 = (bx & 31) * 2;

    for (int q = t; q < 512; q += 256) {
        const int b = q >> 8, i = q & 255;
        FS[q] = ((const float4*)(fs + (size_t)(b0 + b) * 1024))[i];
    }
    for (int q = t; q < 1024; q += 256) {
        const int b = q >> 9, i = q & 511;
        FT[q] = ((const float4*)(ft + (size_t)(b0 + b) * 2048))[i];
    }
    __syncthreads();

    const int w = t >> 6, lane = t & 63;
    const int d = dq * 4 + w;                  // one dim per wave

    {   // s-side
        const float4* wrow = (const float4*)(Ws + (size_t)d * 1024);
        float a0 = 0.0f, a1 = 0.0f;
        #pragma unroll
        for (int i = 0; i < 4; ++i) {
            const float4 wv = wrow[i * 64 + lane];
            a0 = dot4(wv, FS[i * 64 + lane], a0);
            a1 = dot4(wv, FS[256 + i * 64 + lane], a1);
        }
        a0 = wave_reduce64(a0) + bs[d];
        a1 = wave_reduce64(a1) + bs[d];
        if (lane == 0) {
            vraw_s[(size_t)b0 * 128 + d]       = a0;
            vraw_s[(size_t)(b0 + 1) * 128 + d] = a1;
            NR[w * 4 + 0] = a0 * a0;
            NR[w * 4 + 1] = a1 * a1;
        }
    }
    {   // t-side
        const float4* wrow = (const float4*)(Wt + (size_t)d * 2048);
        float a0 = 0.0f, a1 = 0.0f;
        #pragma unroll
        for (int i = 0; i < 8; ++i) {
            const float4 wv = wrow[i * 64 + lane];
            a0 = dot4(wv, FT[i * 64 + lane], a0);
            a1 = dot4(wv, FT[512 + i * 64 + lane], a1);
        }
        a0 = wave_reduce64(a0) + bt[d];
        a1 = wave_reduce64(a1) + bt[d];
        if (lane == 0) {
            vraw_t[(size_t)b0 * 128 + d]       = a0;
            vraw_t[(size_t)(b0 + 1) * 128 + d] = a1;
            NR[w * 4 + 2] = a0 * a0;
            NR[w * 4 + 3] = a1 * a1;
        }
    }
    __syncthreads();
    if (t < 4) {
        // t=0: s-side b0 | t=1: s-side b0+1 | t=2: t-side b0 | t=3: t-side b0+1
        const float v = NR[0 * 4 + t] + NR[1 * 4 + t] + NR[2 * 4 + t] + NR[3 * 4 + t];
        const int side = (t < 2) ? 1 : 0;      // side0 = t-bank, side1 = s-bank
        const int bb = b0 + (t & 1);
        n2part[side * 2048 + bb * 32 + dq] = v;
    }
}

// ---------------- fused bf16 MFMA GEMM + weighted exp-sum (no S array) -------
// lane (m,q4) reg j of the (swapped) D-frag = S[row0+m][b = n*16+q4*4+j]
// (mapping verified R2-R9). 2-buffer register pipeline; grid (512,2) = 2048
// waves/bank; 3 unconditional chunks + wave-uniform-guarded 4th. Prologue
// computes scale[b] = INV_T*rsqrt(sum_dq n2part).
// R12 lesson: LDS-V + launch_bounds(256,5) made the compiler spill the A
// staging buffer (WRITE_SIZE 32KB -> 56MB, dur 44 -> 62us). This register
// build (VGPR 116, ~16% occ) runs at 2.65 TB/s combined service -- above the
// textbook probe's 2.35 TB/s pure-HBM rate (R11) -- i.e. at the platform's
// measured service floor for this working set.
#define SG_ISSUE(AB, CB, CID)                                                \
  {                                                                          \
    const int r0_ = (CID) << 4;                                              \
    const float4* ar_ = (const float4*)(bankp + (size_t)(r0_ + m) * 128);    \
    _Pragma("unroll")                                                        \
    for (int kk = 0; kk < 4; ++kk) {                                         \
      AB[kk * 2]     = ar_[(kk * 4 + q4) * 2];                               \
      AB[kk * 2 + 1] = ar_[(kk * 4 + q4) * 2 + 1];                           \
    }                                                                        \
    _Pragma("unroll")                                                        \
    for (int n = 0; n < 4; ++n)                                              \
      CB[n] = cntw[(size_t)(n * 4 + q4) * NDATA + (r0_ + m)];                \
  }

#define SG_PROCESS(AB, CB)                                                   \
  {                                                                          \
    short8 af_[4];                                                           \
    _Pragma("unroll")                                                        \
    for (int kk = 0; kk < 4; ++kk)                                           \
      af_[kk] = pack_bf16(AB[kk * 2], AB[kk * 2 + 1]);                       \
    _Pragma("unroll")                                                        \
    for (int n = 0; n < 4; ++n) {                                            \
      f32x4 av = {0.f, 0.f, 0.f, 0.f};                                       \
      _Pragma("unroll")                                                      \
      for (int kk = 0; kk < 4; ++kk)                                         \
        av = __builtin_amdgcn_mfma_f32_16x16x32_bf16(bfv[n][kk], af_[kk], av, 0, 0, 0); \
      const unsigned cw_ = CB[n];                                            \
      _Pragma("unroll")                                                      \
      for (int j = 0; j < 4; ++j) {                                          \
        const float fm_ = (float)((cw_ >> (8 * j)) & 255u);                  \
        const float e_  = __expf(av[j] * scv[n][j]);                         \
        se  = fmaf(e_, fm_, se);                                             \
        se2 = fmaf(e_ * fm_, e_, se2);                                       \
      }                                                                      \
    }                                                                        \
  }

__global__ __launch_bounds__(256) void sgemm_kernel(
    const float* __restrict__ m1, const float* __restrict__ m2,
    const float* __restrict__ vraw_s, const float* __restrict__ vraw_t,
    const float* __restrict__ n2part,
    const unsigned* __restrict__ cntw,
    float* __restrict__ acc)
{
    const int t = threadIdx.x;
    const int bank = blockIdx.y;
    const float* __restrict__ bankp = bank ? m2 : m1;
    const float* __restrict__ vp    = bank ? vraw_s : vraw_t;

    __shared__ float scl[64];
    {   // prologue: scale[b] = INV_T * rsqrt(sum_dq n2part[bank][b][dq])
        const int tb = t >> 2, tg = t & 3;     // 4 threads per b
        const float* np = n2part + bank * 2048 + tb * 32 + tg * 8;
        float s = 0.0f;
        #pragma unroll
        for (int j = 0; j < 8; ++j) s += np[j];
        s += __shfl_xor(s, 1);
        s += __shfl_xor(s, 2);
        if (tg == 0) scl[tb] = INV_T * rsqrtf(s);
    }
    __syncthreads();

    const int lane = t & 63;
    const int m  = lane & 15;
    const int q4 = lane >> 4;

    // V fragments, register-resident
    short8 bfv[4][4];
    #pragma unroll
    for (int n = 0; n < 4; ++n) {
        const float4* vrow = (const float4*)(vp + (size_t)(n * 16 + m) * 128);
        #pragma unroll
        for (int kk = 0; kk < 4; ++kk) {
            const float4 lo = vrow[(kk * 4 + q4) * 2];
            const float4 hi = vrow[(kk * 4 + q4) * 2 + 1];
            bfv[n][kk] = pack_bf16(lo, hi);
        }
    }

    // per-lane scales for its 16 b's
    f32x4 scv[4];
    #pragma unroll
    for (int n = 0; n < 4; ++n) {
        #pragma unroll
        for (int j = 0; j < 4; ++j) scv[n][j] = scl[n * 16 + q4 * 4 + j];
    }

    float se = 0.0f, se2 = 0.0f;

    const int wave = (blockIdx.x << 2) | (t >> 6);   // 0..2047

    float4 aA[8], aB[8];
    unsigned cA[4], cB[4];

    SG_ISSUE(aA, cA, wave);
    SG_ISSUE(aB, cB, wave + SG_NW);
    SG_PROCESS(aA, cA);
    SG_ISSUE(aA, cA, wave + 2 * SG_NW);
    SG_PROCESS(aB, cB);
    if (wave + 3 * SG_NW < NCHUNKS) {                // wave-uniform (106 waves)
        SG_ISSUE(aB, cB, wave + 3 * SG_NW);
        SG_PROCESS(aA, cA);
        SG_PROCESS(aB, cB);
    } else {
        SG_PROCESS(aA, cA);
    }

    se  = wave_reduce64(se);
    se2 = wave_reduce64(se2);
    __shared__ float red[4][2];
    if (lane == 0) { red[t >> 6][0] = se; red[t >> 6][1] = se2; }
    __syncthreads();
    if (t < 2) {
        const float s = red[0][t] + red[1][t] + red[2][t] + red[3][t];
        atomicAdd(&acc[(blockIdx.x & (ACC_GROUPS - 1)) * ACC_STRIDE + bank * 2 + t], s);
    }
}

// ---------------- final: positives (direct dots) + closed-form negatives -----
__global__ __launch_bounds__(256) void final_kernel(
    const int* __restrict__ idx,
    const float* __restrict__ m1, const float* __restrict__ m2,
    const float* __restrict__ vraw_t, const float* __restrict__ vraw_s,
    const float* __restrict__ n2part,
    const float* __restrict__ acc, float* __restrict__ out)
{
    const int t = threadIdx.x, wave = t >> 6, lane = t & 63, g = lane >> 4, li = lane & 15;
    __shared__ float sctl[64], scsl[64];
    __shared__ float e1s[64], e2s[64];

    if (t < 128) {                             // scales from n2part
        const int side = t >> 6, b = t & 63;   // side0 = t-bank, side1 = s-bank
        const float* np = n2part + side * 2048 + b * 32;
        float s = 0.0f;
        for (int j = 0; j < 32; ++j) s += np[j];
        (side ? scsl : sctl)[b] = INV_T * rsqrtf(s);
    }
    __syncthreads();

    #pragma unroll
    for (int i = 0; i < 4; ++i) {
        const int b = wave * 16 + i * 4 + g;
        const int row = idx[b];
        float dT = dot8bf((const float4*)(m1 + (size_t)row * 128),
                          (const float4*)(vraw_t + (size_t)b * 128), li, 0.f);
        float dS = dot8bf((const float4*)(m2 + (size_t)row * 128),
                          (const float4*)(vraw_s + (size_t)b * 128), li, 0.f);
        dT = group_reduce16(dT);
        dS = group_reduce16(dS);
        if (li == 0) {
            e1s[b] = __expf(dT * sctl[b]);
            e2s[b] = __expf(dS * scsl[b]);
        }
    }
    __syncthreads();

    if (t < 64) {
        const int b = t;
        const float c = 0.16384f + 1e-7f;
        const float e1p = e1s[b], e2p = e2s[b];

        const float pseT = wave_reduce64(e1p);
        const float pseS = wave_reduce64(e2p);

        float seT_neg = 0.f, se2T_neg = 0.f, seS_neg = 0.f, se2S_neg = 0.f;
        for (int s = 0; s < ACC_GROUPS; ++s) {
            seT_neg  += acc[s * ACC_STRIDE + 0];
            se2T_neg += acc[s * ACC_STRIDE + 1];
            seS_neg  += acc[s * ACC_STRIDE + 2];
            se2S_neg += acc[s * ACC_STRIDE + 3];
        }

        const float zn = (float)PTOT / (float)NDATA;
        const float invZt = zn / (seT_neg + pseT);   // Z-sum includes positives
        const float invZs = zn / (seS_neg + pseS);

        const float PB = (float)(PTOT - BSZ);        // 1,048,576
        const float LOG_MPN_C = -6.1035156e-7f;      // ln(mPn / (mPn + 1e-7))
        const float ic = 1.0f / c;

        const float negT = PB * LOG_MPN_C
                         - seT_neg * invZt * ic
                         + 0.5f * se2T_neg * invZt * invZt * ic * ic;
        const float negS = PB * LOG_MPN_C
                         - seS_neg * invZs * ic
                         + 0.5f * se2S_neg * invZs * invZs * ic * ic;

        const float x0t = e1p * invZt, x0s = e2p * invZs;
        float pos = __logf(x0t / (x0t + c)) + __logf(x0s / (x0s + c));
        pos = wave_reduce64(pos);

        if (b == 0) out[0] = -(negT + negS + pos) * (1.0f / 64.0f);
    }
}

extern "C" void kernel_launch(void* const* d_in, const int* in_sizes, int n_in,
                              void* d_out, int out_size, void* d_ws, size_t ws_size,
                              hipStream_t stream) {
    const float* fs   = (const float*)d_in[0];
    const float* ft   = (const float*)d_in[1];
    const int*   idx  = (const int*)d_in[2];
    const int*   cidx = (const int*)d_in[3];
    const float* Ws   = (const float*)d_in[4];
    const float* bs   = (const float*)d_in[5];
    const float* Wt   = (const float*)d_in[6];
    const float* bt   = (const float*)d_in[7];
    const float* m1   = (const float*)d_in[8];
    const float* m2   = (const float*)d_in[9];
    float* out = (float*)d_out;

    // ws layout (float index):
    //   [0..2048)            acc (32 groups x 64-float line; zeroed by embed blocks)
    //   [2048..6144)         n2part (2 sides x 64 b x 32 dq)
    //   [6144..8192)         pad
    //   [8192..1608192)      cnt_w (16 w-groups x 100000 u32 = 6.4 MB; fully written)
    //   [1608192..1616384)   vraw_s
    //   [1616384..1624576)   vraw_t
    float* ws      = (float*)d_ws;
    float* acc     = ws;
    float* n2part  = ws + 2048;
    unsigned* cntw = (unsigned*)(ws + 8192);
    float* vraw_s  = ws + 1608192;
    float* vraw_t  = ws + 1616384;

    embedhist_kernel<<<dim3(1152), dim3(256), 0, stream>>>(
        fs, ft, Ws, bs, Wt, bt, cidx, vraw_s, vraw_t, n2part, cntw, acc);
    sgemm_kernel<<<dim3(512, 2), dim3(256), 0, stream>>>(   // grid MUST match SG_NW
        m1, m2, vraw_s, vraw_t, n2part, cntw, acc);
    final_kernel<<<dim3(1), dim3(256), 0, stream>>>(
        idx, m1, m2, vraw_t, vraw_s, n2part, acc, out);
}